// Round 12
// baseline (181.270 us; speedup 1.0000x reference)
//
#include <hip/hip_runtime.h>

// ---------------- problem constants ----------------
#define BATCH   65536
#define NPAGES  4096
#define KD      128

// ws layout (bytes). Total 18,309,120 B (~17.5 MB).
#define OFF_Q    0u          // Q bf16 frag-packed [2048 tiles][8 ks][64 lanes]*16B  16 MB
#define OFF_K    16777216u   // K bf16 frag-packed [128 tiles][8 ks][64 lanes]*16B    1 MB
#define OFF_V    17825792u   // V-fragA [256 g][64 lanes]*16B (vcols 0-31)          256 KB
#define OFF_VB   18087936u   // V-fragB compact [256 g][32]*16B (vcols 32-47+aug)   128 KB
#define OFF_W1T  18219008u   // W1^T bf16 [256][48] (k padded 36->48)                24 KB
#define OFF_W2T  18243584u   // W2^T bf16 [128][256]                                 64 KB
#define WS_NEEDED 18309120u

typedef short          bfr8   __attribute__((ext_vector_type(8)));
typedef unsigned short u16x8  __attribute__((ext_vector_type(8)));
typedef unsigned short u16x4  __attribute__((ext_vector_type(4)));
typedef unsigned int   u32x4  __attribute__((ext_vector_type(4)));
typedef float          f32x16v __attribute__((ext_vector_type(16)));

__device__ __forceinline__ unsigned short f2bf(float x){
  unsigned int u = __builtin_bit_cast(unsigned int, x);
  unsigned int r = (u + 0x7fffu + ((u >> 16) & 1u)) >> 16;   // RNE
  return (unsigned short)r;
}
__device__ __forceinline__ float sigmoidf_(float x){ return 1.0f / (1.0f + __expf(-x)); }

__device__ __forceinline__ f32x16v mfma32(bfr8 a, bfr8 b, f32x16v c){
  return __builtin_amdgcn_mfma_f32_32x32x16_bf16(a, b, c, 0, 0, 0);
}
__device__ __forceinline__ f32x16v zero16(){
  f32x16v v;
  #pragma unroll
  for (int i = 0; i < 16; ++i) v[i] = 0.f;
  return v;
}

// async global->LDS, 16B per lane, dest = ldsbase + lane*16 (linear)
__device__ __forceinline__ void glds16(const void* g, void* l){
  __builtin_amdgcn_global_load_lds(
      (const __attribute__((address_space(1))) unsigned int*)g,
      (__attribute__((address_space(3))) unsigned int*)l, 16, 0, 0);
}

// exp2 + pack one 32-key S^T-tile into two PV A-fragments (keys 0-15, 16-31).
// Q pre-scaled by invt*log2e -> P = exp2(S) directly.
__device__ __forceinline__ void tile_pack(const f32x16v& s, bfr8& paA, bfr8& paB){
  unsigned w[8];
  #pragma unroll
  for (int p = 0; p < 8; ++p){
    float a = exp2f(s[2*p]);
    float b = exp2f(s[2*p+1]);
    asm("v_cvt_pk_bf16_f32 %0, %1, %2" : "=v"(w[p]) : "v"(a), "v"(b));
  }
  asm("v_permlane32_swap_b32 %0, %1" : "+v"(w[0]), "+v"(w[2]));
  asm("v_permlane32_swap_b32 %0, %1" : "+v"(w[1]), "+v"(w[3]));
  asm("v_permlane32_swap_b32 %0, %1" : "+v"(w[4]), "+v"(w[6]));
  asm("v_permlane32_swap_b32 %0, %1" : "+v"(w[5]), "+v"(w[7]));
  u32x4 t0 = {w[0], w[1], w[2], w[3]};
  u32x4 t1 = {w[4], w[5], w[6], w[7]};
  paA = __builtin_bit_cast(bfr8, t0);
  paB = __builtin_bit_cast(bfr8, t1);
}

// ---------------- prep: bf16 conversions / fragment-packed layouts ----------
// 135168 threads (528 x 256), exact segments.
__global__ void prep_kernel(const float* __restrict__ mappings, const float* __restrict__ keys,
                            const float* __restrict__ perms, const float* __restrict__ W1,
                            const float* __restrict__ W2, char* __restrict__ ws){
  int t = blockIdx.x * 256 + threadIdx.x;
  if (t < 65536){                       // K-frag: page p, dim-octet c8
    int p = t >> 4, c8 = t & 15;
    const float* src = keys + (size_t)p * 128 + c8 * 8;
    u16x8 val;
    #pragma unroll
    for (int j = 0; j < 8; ++j) val[j] = f2bf(src[j]);
    int ks = c8 >> 1, hi2 = c8 & 1;
    int t32 = p >> 5, lo = p & 31;
    *(u16x8*)(ws + OFF_K + (((size_t)t32 * 8 + ks) * 64 + hi2 * 32 + lo) * 16) = val;
  } else if (t < 65536 + 12288){        // W1^T [256][48], k>=36 zero
    int i = t - 65536; int cc = i / 48, k = i - cc * 48;
    float v = (k < 36) ? W1[(size_t)k * 256 + cc] : 0.0f;
    ((unsigned short*)(ws + OFF_W1T))[cc * 48 + k] = f2bf(v);
  } else if (t < 65536 + 12288 + 32768){ // W2^T [128][256]
    int i = t - (65536 + 12288); int cc = i >> 8, k = i & 255;
    ((unsigned short*)(ws + OFF_W2T))[cc * 256 + k] = f2bf(W2[(size_t)k * 128 + cc]);
  } else if (t < 110592 + 16384){       // V-fragA: vcols 0..31 (all < 36 -> mappings)
    int i = t - 110592;
    int g = i >> 6, lane = i & 63, lo = lane & 31, hi = lane >> 5;
    u16x8 val;
    #pragma unroll
    for (int j = 0; j < 8; ++j){
      int p = 16 * g + 8 * hi + j;
      val[j] = f2bf(mappings[(size_t)p * 72 + 36 + lo]);
    }
    *(u16x8*)(ws + OFF_V + (size_t)i * 16) = val;
  } else {                              // V-fragB compact: vcols 32..47 (aug col 40 = ones)
    int i = t - 126976;                 // [0, 8192)
    int g = i >> 5, idx = i & 31, hi = idx >> 4, l4 = idx & 15;
    int vcol = 32 + l4;
    u16x8 val;
    #pragma unroll
    for (int j = 0; j < 8; ++j){
      int p = 16 * g + 8 * hi + j;
      float v;
      if (vcol < 36)       v = mappings[(size_t)p * 72 + 36 + vcol];
      else if (vcol < 40)  v = perms[(size_t)p * 4 + (vcol - 36)];
      else if (vcol == 40) v = 1.0f;
      else                 v = 0.0f;
      val[j] = f2bf(v);
    }
    *(u16x8*)(ws + OFF_VB + (size_t)i * 16) = val;
  }
}

// ---------------- MLP: query = gelu(pb@W1+b1)@W2+b2 -> Q frag-packed -------
__global__ __launch_bounds__(256, 2) void mlp_kernel(const float* __restrict__ vab,
    const float* __restrict__ b1, const float* __restrict__ b2,
    const float* __restrict__ temp_p, char* __restrict__ ws, float* __restrict__ out){
  __shared__ __align__(16) unsigned short pb_lds[128 * 64];   // swizzled bf16, 16 KB
  __shared__ __align__(16) unsigned short h_lds[128 * 256];   // swizzled bf16, 64 KB
  const int tid = threadIdx.x;
  const int bb = blockIdx.x * 128;
  const float qscale = 1.44269504088896f / fmaxf(fabsf(temp_p[0]), 0.1f);

  for (int i = tid; i < 128 * 64; i += 256){                  // stage page bits (pad k 36..63 = 0)
    int r = i >> 6, k = i & 63;
    float v = (k < 36) ? vab[(size_t)(bb + r) * 48 + 12 + k] : 0.0f;
    int byte = (r * 128 + k * 2) ^ ((r & 7) << 4);
    *(unsigned short*)((char*)pb_lds + byte) = f2bf(v);
  }
  for (int i = tid; i < 128 * 12; i += 256){                  // offset-bit passthrough
    int r = i / 12, c = i - r * 12;
    out[(size_t)(bb + r) * 52 + c] = vab[(size_t)(bb + r) * 48 + c];
  }
  __syncthreads();

  const int lane = tid & 63, wv = tid >> 6;
  const int lo = lane & 31, hi = lane >> 5;
  const unsigned short* w1t = (const unsigned short*)(ws + OFF_W1T);

  // phase 1: h^T = W1^T @ pb^T
  #pragma unroll
  for (int art = 0; art < 2; ++art){
    const int hcol0 = (wv * 2 + art) * 32;
    bfr8 af[3];
    #pragma unroll
    for (int ks = 0; ks < 3; ++ks)
      af[ks] = *(const bfr8*)(w1t + (size_t)(hcol0 + lo) * 48 + 8 * hi + 16 * ks);
    for (int bct = 0; bct < 4; ++bct){
      f32x16v acc = zero16();
      #pragma unroll
      for (int ks = 0; ks < 3; ++ks){
        int row = bct * 32 + lo;
        int byte = row * 128 + ((16 * hi + 32 * ks) ^ ((row & 7) << 4));
        bfr8 bf = *(const bfr8*)((const char*)pb_lds + byte);
        acc = mfma32(af[ks], bf, acc);
      }
      int brow = bct * 32 + lo;
      #pragma unroll
      for (int w = 0; w < 4; ++w){
        u16x4 pk;
        #pragma unroll
        for (int rs = 0; rs < 4; ++rs){
          int hcol = hcol0 + rs + 8 * w + 4 * hi;
          float x = acc[4 * w + rs] + b1[hcol];
          // tanh-form gelu (|x| <~ 1 here; diff vs erf-gelu < 1e-4)
          float u = x * (0.7978845608028654f + 0.0356774081f * x * x);
          float t = exp2f(u * -2.885390081777927f);   // e^{-2u}
          float th = (1.0f - t) / (1.0f + t);
          pk[rs] = f2bf(0.5f * x * (1.0f + th));
        }
        int byte = (brow * 512 + (hcol0 + 8 * w + 4 * hi) * 2) ^ ((brow & 7) << 4);
        *(u16x4*)((char*)h_lds + byte) = pk;
      }
    }
  }
  __syncthreads();

  // phase 2: q^T = W2^T @ h^T -> Q frag-packed bf16 (folded invt*log2e)
  const unsigned short* w2t = (const unsigned short*)(ws + OFF_W2T);
  const int qcol0 = wv * 32;
  bfr8 af2[16];
  #pragma unroll
  for (int ks = 0; ks < 16; ++ks)
    af2[ks] = *(const bfr8*)(w2t + (size_t)(qcol0 + lo) * 256 + 8 * hi + 16 * ks);
  for (int bct = 0; bct < 4; ++bct){
    f32x16v acc = zero16();
    int brow = bct * 32 + lo;
    #pragma unroll
    for (int ks = 0; ks < 16; ++ks){
      int byte = brow * 512 + ((16 * hi + 32 * ks) ^ ((brow & 7) << 4));
      bfr8 bf = *(const bfr8*)((const char*)h_lds + byte);
      acc = mfma32(af2[ks], bf, acc);
    }
    int t32 = (bb + brow) >> 5;           // lo5 == lo (bb multiple of 128)
    #pragma unroll
    for (int w = 0; w < 4; ++w){
      u16x4 pk;
      #pragma unroll
      for (int rs = 0; rs < 4; ++rs){
        int qcol = qcol0 + rs + 8 * w + 4 * hi;
        pk[rs] = f2bf((acc[4 * w + rs] + b2[qcol]) * qscale);
      }
      int qs = qcol0 + 8 * w + 4 * hi;    // start col of this 4-run
      int ks2 = qs >> 4, hb = (qs >> 3) & 1;
      *(u16x4*)(ws + OFF_Q + (((size_t)t32 * 8 + ks2) * 64 + hb * 32 + lo) * 16
                + (qs & 4) * 2) = pk;
    }
  }
}

// ---------------- attention: single-tile/wave, K-split-2, async pipeline ---
// 1024 WGs x 256 thr (4 waves). wave = (sub = 32-row tile, half = K-half).
// Half h: 64 iters of 32 pages; K staged via glds16 into 2x8KB dbuf; ONE raw
// s_barrier per iter; stage(c+1) stays in flight across pack+PV+barrier.
// Q in registers; V frag-packed direct from L2. VGPR ~116 -> 4 waves/SIMD.
__global__ __launch_bounds__(256, 4) void attn_kernel(const char* __restrict__ ws,
    float* __restrict__ out){
  __shared__ __align__(16) char smem[32768];    // [half][buf][8KB]; epilogue overlay

  const int tid = threadIdx.x;
  const int lane = tid & 63, wv = tid >> 6;
  const int sub = wv & 1, half = wv >> 1;
  const int lo = lane & 31, hi = lane >> 5;
  const int bb = blockIdx.x * 64;

  const char* qfg = ws + OFF_Q;
  const char* kf  = ws + OFF_K;
  const char* va  = ws + OFF_V;
  const char* vb  = ws + OFF_VB;

  const int qtile = (bb >> 5) + sub;
  bfr8 qf[8];                                   // Q tile in registers (B-frag)
  #pragma unroll
  for (int ks = 0; ks < 8; ++ks)
    qf[ks] = *(const bfr8*)(qfg + (size_t)qtile * 8192 + ks * 1024 + lane * 16);

  f32x16v acc0 = zero16(), acc1 = zero16();

  char* kbuf = smem + half * 16384;             // this half's 2 x 8 KB dbuf
  const int tb = half * 64;                     // first 32-page tile index

  // prologue: stage tile tb into buf 0 (each wave covers sub*4KB)
  #pragma unroll
  for (int i = 0; i < 4; ++i)
    glds16(kf + (size_t)tb * 8192 + sub * 4096 + lane * 16 + i * 1024,
           kbuf + sub * 4096 + i * 1024);

  for (int c = 0; c < 64; ++c){
    // drain this wave's stage(c) (issued last iter; had pack+PV to complete),
    // then raw barrier: buf(c) visible to both waves. No full pipeline drain.
    asm volatile("s_waitcnt vmcnt(0)" ::: "memory");
    __builtin_amdgcn_sched_barrier(0);
    __builtin_amdgcn_s_barrier();
    __builtin_amdgcn_sched_barrier(0);

    const char* kb = kbuf + (c & 1) * 8192;
    f32x16v s = zero16();
    #pragma unroll
    for (int ks = 0; ks < 8; ++ks){
      bfr8 k0 = *(const bfr8*)(kb + ks * 1024 + lane * 16);
      s = mfma32(k0, qf[ks], s);
    }
    __builtin_amdgcn_sched_barrier(0);          // QK ds_reads complete above

    // issue next-tile DMA (in flight across pack/PV and the next barrier)
    {
      int tn = tb + ((c < 63) ? c + 1 : 63);
      const char* src = kf + (size_t)tn * 8192 + sub * 4096 + lane * 16;
      char* dst = kbuf + ((c + 1) & 1) * 8192 + sub * 4096;
      #pragma unroll
      for (int i = 0; i < 4; ++i) glds16(src + i * 1024, dst + i * 1024);
    }

    // V fragments (frag-packed, L2-resident; compiler inserts counted vmcnt)
    const int t = tb + c;
    const char* vg  = va + (size_t)t * 2048 + lane * 16;
    const char* vgb = vb + (size_t)t * 1024 + (hi * 16 + (lo & 15)) * 16;
    bfr8 vA0 = *(const bfr8*)(vg);
    bfr8 vA1 = *(const bfr8*)(vg + 1024);
    bfr8 vB0 = *(const bfr8*)(vgb);
    bfr8 vB1 = *(const bfr8*)(vgb + 512);

    bfr8 p0, p1;
    tile_pack(s, p0, p1);                       // pages 0-15, 16-31 of tile
    acc0 = mfma32(p0, vA0, acc0);  acc0 = mfma32(p1, vA1, acc0);
    acc1 = mfma32(p0, vB0, acc1);  acc1 = mfma32(p1, vB1, acc1);
  }

  // ---- combine halves via LDS overlay (K buffers dead; drain DMA first) ----
  __syncthreads();
  float* comb0 = (float*)smem;                  // [2][32][32] f32, 8 KB
  float* comb1 = (float*)(smem + 8192);         // [2][32][12] f32, 3 KB
  if (half == 1){
    #pragma unroll
    for (int r = 0; r < 16; ++r){
      int rl = (r & 3) + 8 * (r >> 2) + 4 * hi;
      comb0[sub * 1024 + rl * 32 + lo] = acc0[r];
      if (lo < 9) comb1[sub * 384 + rl * 12 + lo] = acc1[r];
    }
  }
  __syncthreads();
  if (half == 0){
    #pragma unroll
    for (int r = 0; r < 16; ++r){
      int rl = (r & 3) + 8 * (r >> 2) + 4 * hi;
      float n0 = acc0[r] + comb0[sub * 1024 + rl * 32 + lo];
      float a1 = acc1[r] + ((lo < 9) ? comb1[sub * 384 + rl * 12 + lo] : 0.0f);
      float dn = __shfl(a1, (lane & 32) + 8, 64);   // denom = vcol 40 (lo==8)
      float di = 1.0f / dn;
      size_t q = (size_t)(bb + sub * 32 + rl);
      out[q * 52 + 12 + lo] = sigmoidf_(n0 * di);
      if (lo < 8) out[q * 52 + 44 + lo] = sigmoidf_(a1 * di);
    }
  }
}

extern "C" void kernel_launch(void* const* d_in, const int* in_sizes, int n_in,
                              void* d_out, int out_size, void* d_ws, size_t ws_size,
                              hipStream_t stream){
  const float* vab      = (const float*)d_in[0];
  const float* mappings = (const float*)d_in[1];
  const float* keys     = (const float*)d_in[2];
  const float* perms    = (const float*)d_in[3];
  const float* W1       = (const float*)d_in[4];
  const float* b1       = (const float*)d_in[5];
  const float* W2       = (const float*)d_in[6];
  const float* b2       = (const float*)d_in[7];
  const float* temp     = (const float*)d_in[8];
  float* out = (float*)d_out;
  char*  ws  = (char*)d_ws;
  if (ws_size < WS_NEEDED) return;   // loud failure instead of OOB corruption

  prep_kernel<<<528, 256, 0, stream>>>(mappings, keys, perms, W1, W2, ws);
  mlp_kernel<<<512, 256, 0, stream>>>(vab, b1, b2, temp, ws, out);
  attn_kernel<<<1024, 256, 0, stream>>>(ws, out);
}

// Round 13
// 144.894 us; speedup vs baseline: 1.2511x; 1.2511x over previous
//
#include <hip/hip_runtime.h>

// ---------------- problem constants ----------------
#define BATCH   65536
#define NPAGES  4096
#define KD      128

// ws layout (bytes). Total 18,309,120 B (~17.5 MB).
#define OFF_Q    0u          // Q bf16 [65536][128], pre-scaled by invt*log2e  16 MB
#define OFF_K    16777216u   // K bf16, 64-page chunks, XOR-swizzled (r&15)     1 MB
#define OFF_V    17825792u   // V^T bf16 [48][4096] (aug: ones col 40)        384 KB
#define OFF_W1T  18219008u   // W1^T bf16 [256][48] (k padded 36->48)          24 KB
#define OFF_W2T  18243584u   // W2^T bf16 [128][256]                           64 KB
#define WS_NEEDED 18309120u

typedef short          bfr8   __attribute__((ext_vector_type(8)));
typedef unsigned short u16x8  __attribute__((ext_vector_type(8)));
typedef unsigned short u16x4  __attribute__((ext_vector_type(4)));
typedef unsigned int   u32x4  __attribute__((ext_vector_type(4)));
typedef float          f32x16v __attribute__((ext_vector_type(16)));

__device__ __forceinline__ unsigned short f2bf(float x){
  unsigned int u = __builtin_bit_cast(unsigned int, x);
  unsigned int r = (u + 0x7fffu + ((u >> 16) & 1u)) >> 16;   // RNE
  return (unsigned short)r;
}
__device__ __forceinline__ float sigmoidf_(float x){ return 1.0f / (1.0f + __expf(-x)); }

__device__ __forceinline__ f32x16v mfma32(bfr8 a, bfr8 b, f32x16v c){
  return __builtin_amdgcn_mfma_f32_32x32x16_bf16(a, b, c, 0, 0, 0);
}
__device__ __forceinline__ f32x16v zero16(){
  f32x16v v;
  #pragma unroll
  for (int i = 0; i < 16; ++i) v[i] = 0.f;
  return v;
}

// async global->LDS, 16B per lane, dest = ldsbase + lane*16 (linear, preserves pre-swizzle)
__device__ __forceinline__ void glds16(const void* g, void* l){
  __builtin_amdgcn_global_load_lds(
      (const __attribute__((address_space(1))) unsigned int*)g,
      (__attribute__((address_space(3))) unsigned int*)l, 16, 0, 0);
}

// Schraudolph exp2 -> bf16, pair-packed. Q pre-scaled by invt*log2e, so
// P = exp2(S). u = (uint)(s*2^23 + (127<<23 - 294336)); bf16 = u>>16.
// Max relative error +-3.5% (vs bf16's inherent 0.4%); numerator/denominator
// errors correlate and average out over 4096 near-uniform weights.
// Cost: pure full-rate VALU (2 fma + 2 cvt + 1 perm per pair) -> zero trans-pipe use.
__device__ __forceinline__ void tile_pack(const f32x16v& s, bfr8& paA, bfr8& paB){
  const float SC = 8388608.0f;        // 2^23
  const float MG = 1065058880.0f;     // (127<<23) - 294336, exactly representable
  unsigned w[8];
  #pragma unroll
  for (int p = 0; p < 8; ++p){
    unsigned ua = (unsigned)fmaf(s[2*p],   SC, MG);
    unsigned ub = (unsigned)fmaf(s[2*p+1], SC, MG);
    w[p] = __builtin_amdgcn_perm(ub, ua, 0x07060302u);  // [ua.hi16 | ub.hi16]
  }
  asm("v_permlane32_swap_b32 %0, %1" : "+v"(w[0]), "+v"(w[2]));
  asm("v_permlane32_swap_b32 %0, %1" : "+v"(w[1]), "+v"(w[3]));
  asm("v_permlane32_swap_b32 %0, %1" : "+v"(w[4]), "+v"(w[6]));
  asm("v_permlane32_swap_b32 %0, %1" : "+v"(w[5]), "+v"(w[7]));
  u32x4 t0 = {w[0], w[1], w[2], w[3]};
  u32x4 t1 = {w[4], w[5], w[6], w[7]};
  paA = __builtin_bit_cast(bfr8, t0);
  paB = __builtin_bit_cast(bfr8, t1);
}

// ---------------- prep: bf16 conversions / layouts ----------------
__global__ void prep_kernel(const float* __restrict__ mappings, const float* __restrict__ keys,
                            const float* __restrict__ perms, const float* __restrict__ W1,
                            const float* __restrict__ W2, char* __restrict__ ws){
  int t = blockIdx.x * 256 + threadIdx.x;
  if (t < 65536){                       // K: 4096 pages x 16 granules of 8 cols
    int p = t >> 4, c8 = t & 15;
    const float* src = keys + (size_t)p * 128 + c8 * 8;
    u16x8 val;
    #pragma unroll
    for (int j = 0; j < 8; ++j) val[j] = f2bf(src[j]);
    int r = p & 63, chunk = p >> 6;
    int byteoff = (r * 256 + c8 * 16) ^ ((r & 15) << 4);  // 16-slot swizzle: 2-way max
    *(u16x8*)(ws + OFF_K + (size_t)chunk * 16384 + byteoff) = val;
  } else if (t < 65536 + 12288){        // W1^T [256][48], k>=36 zero
    int i = t - 65536; int cc = i / 48, k = i - cc * 48;
    float v = (k < 36) ? W1[(size_t)k * 256 + cc] : 0.0f;
    ((unsigned short*)(ws + OFF_W1T))[cc * 48 + k] = f2bf(v);
  } else if (t < 65536 + 12288 + 32768){ // W2^T [128][256]
    int i = t - (65536 + 12288); int cc = i >> 8, k = i & 255;
    ((unsigned short*)(ws + OFF_W2T))[cc * 256 + k] = f2bf(W2[(size_t)k * 128 + cc]);
  } else {                              // V^T [48][4096]: rows 0..35 map[36+j], 36..39 perms, 40 ones, 41..47 zero
    int i = t - (65536 + 12288 + 32768); int j = i >> 12, p = i & 4095;
    float v;
    if (j < 36)      v = mappings[(size_t)p * 72 + 36 + j];
    else if (j < 40) v = perms[(size_t)p * 4 + (j - 36)];
    else if (j == 40) v = 1.0f;
    else             v = 0.0f;
    ((unsigned short*)(ws + OFF_V))[j * 4096 + p] = f2bf(v);
  }
}

// ---------------- MLP: query = gelu(pb@W1+b1)@W2+b2 -> Q bf16 (pre-scaled) --
__global__ __launch_bounds__(256, 2) void mlp_kernel(const float* __restrict__ vab,
    const float* __restrict__ b1, const float* __restrict__ b2,
    const float* __restrict__ temp_p, char* __restrict__ ws, float* __restrict__ out){
  __shared__ __align__(16) unsigned short pb_lds[128 * 64];   // swizzled bf16, 16 KB
  __shared__ __align__(16) unsigned short h_lds[128 * 256];   // swizzled bf16, 64 KB
  const int tid = threadIdx.x;
  const int bb = blockIdx.x * 128;
  const float qscale = 1.44269504088896f / fmaxf(fabsf(temp_p[0]), 0.1f);

  for (int i = tid; i < 128 * 64; i += 256){                  // stage page bits (pad k 36..63 = 0)
    int r = i >> 6, k = i & 63;
    float v = (k < 36) ? vab[(size_t)(bb + r) * 48 + 12 + k] : 0.0f;
    int byte = (r * 128 + k * 2) ^ ((r & 7) << 4);
    *(unsigned short*)((char*)pb_lds + byte) = f2bf(v);
  }
  for (int i = tid; i < 128 * 12; i += 256){                  // offset-bit passthrough
    int r = i / 12, c = i - r * 12;
    out[(size_t)(bb + r) * 52 + c] = vab[(size_t)(bb + r) * 48 + c];
  }
  __syncthreads();

  const int lane = tid & 63, wv = tid >> 6;
  const int lo = lane & 31, hi = lane >> 5;
  const unsigned short* w1t = (const unsigned short*)(ws + OFF_W1T);

  // phase 1: h^T = W1^T @ pb^T
  #pragma unroll
  for (int art = 0; art < 2; ++art){
    const int hcol0 = (wv * 2 + art) * 32;
    bfr8 af[3];
    #pragma unroll
    for (int ks = 0; ks < 3; ++ks)
      af[ks] = *(const bfr8*)(w1t + (size_t)(hcol0 + lo) * 48 + 8 * hi + 16 * ks);
    for (int bct = 0; bct < 4; ++bct){
      f32x16v acc = zero16();
      #pragma unroll
      for (int ks = 0; ks < 3; ++ks){
        int row = bct * 32 + lo;
        int byte = row * 128 + ((16 * hi + 32 * ks) ^ ((row & 7) << 4));
        bfr8 bf = *(const bfr8*)((const char*)pb_lds + byte);
        acc = mfma32(af[ks], bf, acc);
      }
      int brow = bct * 32 + lo;
      #pragma unroll
      for (int w = 0; w < 4; ++w){
        u16x4 pk;
        #pragma unroll
        for (int rs = 0; rs < 4; ++rs){
          int hcol = hcol0 + rs + 8 * w + 4 * hi;
          float x = acc[4 * w + rs] + b1[hcol];
          // tanh-form gelu (|x| <~ 1 here; diff vs erf-gelu < 1e-4)
          float u = x * (0.7978845608028654f + 0.0356774081f * x * x);
          float t = exp2f(u * -2.885390081777927f);   // e^{-2u}
          float th = (1.0f - t) / (1.0f + t);
          pk[rs] = f2bf(0.5f * x * (1.0f + th));
        }
        int byte = (brow * 512 + (hcol0 + 8 * w + 4 * hi) * 2) ^ ((brow & 7) << 4);
        *(u16x4*)((char*)h_lds + byte) = pk;
      }
    }
  }
  __syncthreads();

  // phase 2: q^T = W2^T @ h^T -> Qws bf16 (folded invt*log2e)
  const unsigned short* w2t = (const unsigned short*)(ws + OFF_W2T);
  unsigned short* qws = (unsigned short*)(ws + OFF_Q);
  const int qcol0 = wv * 32;
  bfr8 af2[16];
  #pragma unroll
  for (int ks = 0; ks < 16; ++ks)
    af2[ks] = *(const bfr8*)(w2t + (size_t)(qcol0 + lo) * 256 + 8 * hi + 16 * ks);
  for (int bct = 0; bct < 4; ++bct){
    f32x16v acc = zero16();
    int brow = bct * 32 + lo;
    #pragma unroll
    for (int ks = 0; ks < 16; ++ks){
      int byte = brow * 512 + ((16 * hi + 32 * ks) ^ ((brow & 7) << 4));
      bfr8 bf = *(const bfr8*)((const char*)h_lds + byte);
      acc = mfma32(af2[ks], bf, acc);
    }
    #pragma unroll
    for (int w = 0; w < 4; ++w){
      u16x4 pk;
      #pragma unroll
      for (int rs = 0; rs < 4; ++rs){
        int qcol = qcol0 + rs + 8 * w + 4 * hi;
        pk[rs] = f2bf((acc[4 * w + rs] + b2[qcol]) * qscale);
      }
      *(u16x4*)(qws + (size_t)(bb + brow) * 128 + qcol0 + 8 * w + 4 * hi) = pk;
    }
  }
}

// ---------------- attention: 64 rows/wave dual-tile, K-split-in-WG ---------
// 512 WGs x 256 thr (4 waves). wave = (sub = rows sub*64..+64, half = K-half).
// Per chunk: two key-phases (0-31, 32-63); each K-frag ds_read feeds 2 Q-tiles.
// (R10 structure; tile_pack now Schraudolph VALU-only exp)
__global__ __launch_bounds__(256, 2) void attn_kernel(const char* __restrict__ ws,
    float* __restrict__ out){
  __shared__ __align__(16) char smem[65536];    // [half][buf][16KB]; epilogue overlay

  const int tid = threadIdx.x;
  const int lane = tid & 63, wv = tid >> 6;
  const int half = wv >> 1, sub = wv & 1;
  const int lo = lane & 31, hi = lane >> 5;
  const int bb = blockIdx.x * 128;

  const unsigned short* qws = (const unsigned short*)(ws + OFF_Q);
  const char* kbase = ws + OFF_K;
  const unsigned short* vt  = (const unsigned short*)(ws + OFF_V);

  const int r0 = bb + sub * 64;
  bfr8 qfA[8], qfB[8];                          // two Q-tiles (B-frag: col=lo)
  #pragma unroll
  for (int ks = 0; ks < 8; ++ks){
    qfA[ks] = *(const bfr8*)(qws + (size_t)(r0 + lo) * 128 + 16 * ks + 8 * hi);
    qfB[ks] = *(const bfr8*)(qws + (size_t)(r0 + 32 + lo) * 128 + 16 * ks + 8 * hi);
  }

  f32x16v accA0 = zero16(), accA1 = zero16();
  f32x16v accB0 = zero16(), accB1 = zero16();

  char* myk = smem + half * 32768;
  const int cbase = half * 32;

  // prologue: stage this half's first chunk into buf 0 (wave covers sub*8KB)
  #pragma unroll
  for (int i = 0; i < 8; ++i)
    glds16(kbase + (size_t)cbase * 16384 + sub * 8192 + lane * 16 + i * 1024,
           myk + sub * 8192 + i * 1024);
  __syncthreads();

  for (int c = 0; c < 32; ++c){
    if (c < 31){                                // issue next-chunk DMA
      const char* src = kbase + (size_t)(cbase + c + 1) * 16384 + sub * 8192 + lane * 16;
      char* dst = myk + ((c + 1) & 1) * 16384 + sub * 8192;
      #pragma unroll
      for (int i = 0; i < 8; ++i) glds16(src + i * 1024, dst + i * 1024);
    }

    const char* kb = myk + (c & 1) * 16384;
    const int cg = cbase + c;

    // ---- phase 1: keys 0..31 ----
    {
      f32x16v sA = zero16(), sB = zero16();
      __builtin_amdgcn_s_setprio(1);
      #pragma unroll
      for (int ks = 0; ks < 8; ++ks){
        int cb = (32 * ks + 16 * hi) ^ ((lo & 15) << 4);
        bfr8 k0 = *(const bfr8*)(kb + lo * 256 + cb);
        sA = mfma32(k0, qfA[ks], sA);
        sB = mfma32(k0, qfB[ks], sB);
      }
      __builtin_amdgcn_s_setprio(0);
      bfr8 v00 = *(const bfr8*)(vt + (size_t)lo * 4096 + cg * 64 + 8 * hi);
      bfr8 v01 = *(const bfr8*)(vt + (size_t)lo * 4096 + cg * 64 + 16 + 8 * hi);
      bfr8 v10 = *(const bfr8*)(vt + (size_t)(32 + (lo & 15)) * 4096 + cg * 64 + 8 * hi);
      bfr8 v11 = *(const bfr8*)(vt + (size_t)(32 + (lo & 15)) * 4096 + cg * 64 + 16 + 8 * hi);
      bfr8 p0, p1, p2, p3;
      tile_pack(sA, p0, p1);
      tile_pack(sB, p2, p3);
      __builtin_amdgcn_s_setprio(1);
      accA0 = mfma32(p0, v00, accA0);  accA0 = mfma32(p1, v01, accA0);
      accA1 = mfma32(p0, v10, accA1);  accA1 = mfma32(p1, v11, accA1);
      accB0 = mfma32(p2, v00, accB0);  accB0 = mfma32(p3, v01, accB0);
      accB1 = mfma32(p2, v10, accB1);  accB1 = mfma32(p3, v11, accB1);
      __builtin_amdgcn_s_setprio(0);
    }
    // ---- phase 2: keys 32..63 ----
    {
      f32x16v sA = zero16(), sB = zero16();
      __builtin_amdgcn_s_setprio(1);
      #pragma unroll
      for (int ks = 0; ks < 8; ++ks){
        int cb = (32 * ks + 16 * hi) ^ ((lo & 15) << 4);   // (32+lo)&15 == lo&15
        bfr8 k1 = *(const bfr8*)(kb + (32 + lo) * 256 + cb);
        sA = mfma32(k1, qfA[ks], sA);
        sB = mfma32(k1, qfB[ks], sB);
      }
      __builtin_amdgcn_s_setprio(0);
      bfr8 v00 = *(const bfr8*)(vt + (size_t)lo * 4096 + cg * 64 + 32 + 8 * hi);
      bfr8 v01 = *(const bfr8*)(vt + (size_t)lo * 4096 + cg * 64 + 48 + 8 * hi);
      bfr8 v10 = *(const bfr8*)(vt + (size_t)(32 + (lo & 15)) * 4096 + cg * 64 + 32 + 8 * hi);
      bfr8 v11 = *(const bfr8*)(vt + (size_t)(32 + (lo & 15)) * 4096 + cg * 64 + 48 + 8 * hi);
      bfr8 p0, p1, p2, p3;
      tile_pack(sA, p0, p1);
      tile_pack(sB, p2, p3);
      __builtin_amdgcn_s_setprio(1);
      accA0 = mfma32(p0, v00, accA0);  accA0 = mfma32(p1, v01, accA0);
      accA1 = mfma32(p0, v10, accA1);  accA1 = mfma32(p1, v11, accA1);
      accB0 = mfma32(p2, v00, accB0);  accB0 = mfma32(p3, v01, accB0);
      accB1 = mfma32(p2, v10, accB1);  accB1 = mfma32(p3, v11, accB1);
      __builtin_amdgcn_s_setprio(0);
    }
    __syncthreads();   // drains DMA (vmcnt) + LDS reads; next buffer ready
  }

  // ---- combine halves via LDS overlay (K buffers are dead now) ----
  float* comb0 = (float*)smem;                  // [128][32] f32, 16 KB
  float* comb1 = (float*)(smem + 16384);        // [128][12] f32, 6 KB
  if (half == 1){
    #pragma unroll
    for (int r = 0; r < 16; ++r){
      int rl = sub * 64 + (r & 3) + 8 * (r >> 2) + 4 * hi;
      comb0[rl * 32 + lo] = accA0[r];
      comb0[(rl + 32) * 32 + lo] = accB0[r];
      if (lo < 9){
        comb1[rl * 12 + lo] = accA1[r];
        comb1[(rl + 32) * 12 + lo] = accB1[r];
      }
    }
  }
  __syncthreads();
  if (half == 0){
    #pragma unroll
    for (int r = 0; r < 16; ++r){
      int rl = sub * 64 + (r & 3) + 8 * (r >> 2) + 4 * hi;
      {
        float n0 = accA0[r] + comb0[rl * 32 + lo];
        float a1 = accA1[r] + ((lo < 9) ? comb1[rl * 12 + lo] : 0.0f);
        float dn = __shfl(a1, (lane & 32) + 8, 64);   // denom = vcol 40 (lo==8)
        float di = 1.0f / dn;
        size_t q = (size_t)(bb + rl);
        out[q * 52 + 12 + lo] = sigmoidf_(n0 * di);
        if (lo < 8) out[q * 52 + 44 + lo] = sigmoidf_(a1 * di);
      }
      {
        float n0 = accB0[r] + comb0[(rl + 32) * 32 + lo];
        float a1 = accB1[r] + ((lo < 9) ? comb1[(rl + 32) * 12 + lo] : 0.0f);
        float dn = __shfl(a1, (lane & 32) + 8, 64);
        float di = 1.0f / dn;
        size_t q = (size_t)(bb + rl + 32);
        out[q * 52 + 12 + lo] = sigmoidf_(n0 * di);
        if (lo < 8) out[q * 52 + 44 + lo] = sigmoidf_(a1 * di);
      }
    }
  }
}

extern "C" void kernel_launch(void* const* d_in, const int* in_sizes, int n_in,
                              void* d_out, int out_size, void* d_ws, size_t ws_size,
                              hipStream_t stream){
  const float* vab      = (const float*)d_in[0];
  const float* mappings = (const float*)d_in[1];
  const float* keys     = (const float*)d_in[2];
  const float* perms    = (const float*)d_in[3];
  const float* W1       = (const float*)d_in[4];
  const float* b1       = (const float*)d_in[5];
  const float* W2       = (const float*)d_in[6];
  const float* b2       = (const float*)d_in[7];
  const float* temp     = (const float*)d_in[8];
  float* out = (float*)d_out;
  char*  ws  = (char*)d_ws;
  if (ws_size < WS_NEEDED) return;   // loud failure instead of OOB corruption

  prep_kernel<<<1200, 256, 0, stream>>>(mappings, keys, perms, W1, W2, ws);
  mlp_kernel<<<512, 256, 0, stream>>>(vab, b1, b2, temp, ws, out);
  attn_kernel<<<512, 256, 0, stream>>>(ws, out);
}

// Round 14
// 138.999 us; speedup vs baseline: 1.3041x; 1.0424x over previous
//
#include <hip/hip_runtime.h>

// ---------------- problem constants ----------------
#define BATCH   65536
#define NPAGES  4096
#define KD      128

// ws layout (bytes). Total 18,309,120 B (~17.5 MB).
#define OFF_Q    0u          // Q bf16 [65536][128], pre-scaled by invt*log2e  16 MB
#define OFF_K    16777216u   // K bf16, 64-page chunks, XOR-swizzled (r&15)     1 MB
#define OFF_V    17825792u   // V-fragA [256 g][64 lanes]*16B (vcols 0-31)    256 KB
#define OFF_VB   18087936u   // V-fragB compact [256 g][32]*16B (vcols 32-47+aug) 128 KB
#define OFF_W1T  18219008u   // W1^T bf16 [256][48] (k padded 36->48)          24 KB
#define OFF_W2T  18243584u   // W2^T bf16 [128][256]                           64 KB
#define WS_NEEDED 18309120u

typedef short          bfr8   __attribute__((ext_vector_type(8)));
typedef unsigned short u16x8  __attribute__((ext_vector_type(8)));
typedef unsigned short u16x4  __attribute__((ext_vector_type(4)));
typedef unsigned int   u32x4  __attribute__((ext_vector_type(4)));
typedef float          f32x16v __attribute__((ext_vector_type(16)));

__device__ __forceinline__ unsigned short f2bf(float x){
  unsigned int u = __builtin_bit_cast(unsigned int, x);
  unsigned int r = (u + 0x7fffu + ((u >> 16) & 1u)) >> 16;   // RNE
  return (unsigned short)r;
}
__device__ __forceinline__ float sigmoidf_(float x){ return 1.0f / (1.0f + __expf(-x)); }

__device__ __forceinline__ f32x16v mfma32(bfr8 a, bfr8 b, f32x16v c){
  return __builtin_amdgcn_mfma_f32_32x32x16_bf16(a, b, c, 0, 0, 0);
}
__device__ __forceinline__ f32x16v zero16(){
  f32x16v v;
  #pragma unroll
  for (int i = 0; i < 16; ++i) v[i] = 0.f;
  return v;
}

// async global->LDS, 16B per lane, dest = ldsbase + lane*16 (linear, preserves pre-swizzle)
__device__ __forceinline__ void glds16(const void* g, void* l){
  __builtin_amdgcn_global_load_lds(
      (const __attribute__((address_space(1))) unsigned int*)g,
      (__attribute__((address_space(3))) unsigned int*)l, 16, 0, 0);
}

// Schraudolph exp2 -> bf16, pair-packed. Q pre-scaled by invt*log2e, so
// P = exp2(S). u = (uint)(s*2^23 + (127<<23 - 294336)); bf16 = u>>16.
// Pure full-rate VALU (2 fma + 2 cvt + 1 perm per pair), zero trans-pipe use.
__device__ __forceinline__ void tile_pack(const f32x16v& s, bfr8& paA, bfr8& paB){
  const float SC = 8388608.0f;        // 2^23
  const float MG = 1065058880.0f;     // (127<<23) - 294336
  unsigned w[8];
  #pragma unroll
  for (int p = 0; p < 8; ++p){
    unsigned ua = (unsigned)fmaf(s[2*p],   SC, MG);
    unsigned ub = (unsigned)fmaf(s[2*p+1], SC, MG);
    w[p] = __builtin_amdgcn_perm(ub, ua, 0x07060302u);  // [ua.hi16 | ub.hi16]
  }
  asm("v_permlane32_swap_b32 %0, %1" : "+v"(w[0]), "+v"(w[2]));
  asm("v_permlane32_swap_b32 %0, %1" : "+v"(w[1]), "+v"(w[3]));
  asm("v_permlane32_swap_b32 %0, %1" : "+v"(w[4]), "+v"(w[6]));
  asm("v_permlane32_swap_b32 %0, %1" : "+v"(w[5]), "+v"(w[7]));
  u32x4 t0 = {w[0], w[1], w[2], w[3]};
  u32x4 t1 = {w[4], w[5], w[6], w[7]};
  paA = __builtin_bit_cast(bfr8, t0);
  paB = __builtin_bit_cast(bfr8, t1);
}

// ---------------- prep: bf16 conversions / layouts ----------------
// 135168 threads (528 x 256), exact segments.
__global__ void prep_kernel(const float* __restrict__ mappings, const float* __restrict__ keys,
                            const float* __restrict__ perms, const float* __restrict__ W1,
                            const float* __restrict__ W2, char* __restrict__ ws){
  int t = blockIdx.x * 256 + threadIdx.x;
  if (t < 65536){                       // K: 4096 pages x 16 granules of 8 cols
    int p = t >> 4, c8 = t & 15;
    const float* src = keys + (size_t)p * 128 + c8 * 8;
    u16x8 val;
    #pragma unroll
    for (int j = 0; j < 8; ++j) val[j] = f2bf(src[j]);
    int r = p & 63, chunk = p >> 6;
    int byteoff = (r * 256 + c8 * 16) ^ ((r & 15) << 4);  // 16-slot swizzle: 2-way max
    *(u16x8*)(ws + OFF_K + (size_t)chunk * 16384 + byteoff) = val;
  } else if (t < 65536 + 12288){        // W1^T [256][48], k>=36 zero
    int i = t - 65536; int cc = i / 48, k = i - cc * 48;
    float v = (k < 36) ? W1[(size_t)k * 256 + cc] : 0.0f;
    ((unsigned short*)(ws + OFF_W1T))[cc * 48 + k] = f2bf(v);
  } else if (t < 65536 + 12288 + 32768){ // W2^T [128][256]
    int i = t - (65536 + 12288); int cc = i >> 8, k = i & 255;
    ((unsigned short*)(ws + OFF_W2T))[cc * 256 + k] = f2bf(W2[(size_t)k * 128 + cc]);
  } else if (t < 110592 + 16384){       // V-fragA: vcols 0..31 (all < 36 -> mappings)
    int i = t - 110592;
    int g = i >> 6, lane = i & 63, lo = lane & 31, hi = lane >> 5;
    u16x8 val;
    #pragma unroll
    for (int j = 0; j < 8; ++j){
      int p = 16 * g + 8 * hi + j;
      val[j] = f2bf(mappings[(size_t)p * 72 + 36 + lo]);
    }
    *(u16x8*)(ws + OFF_V + (size_t)i * 16) = val;
  } else {                              // V-fragB compact: vcols 32..47 (aug col 40 = ones)
    int i = t - 126976;                 // [0, 8192)
    int g = i >> 5, idx = i & 31, hi = idx >> 4, l4 = idx & 15;
    int vcol = 32 + l4;
    u16x8 val;
    #pragma unroll
    for (int j = 0; j < 8; ++j){
      int p = 16 * g + 8 * hi + j;
      float v;
      if (vcol < 36)       v = mappings[(size_t)p * 72 + 36 + vcol];
      else if (vcol < 40)  v = perms[(size_t)p * 4 + (vcol - 36)];
      else if (vcol == 40) v = 1.0f;
      else                 v = 0.0f;
      val[j] = f2bf(v);
    }
    *(u16x8*)(ws + OFF_VB + (size_t)i * 16) = val;
  }
}

// ---------------- MLP: query = gelu(pb@W1+b1)@W2+b2 -> Q bf16 (pre-scaled) --
__global__ __launch_bounds__(256, 2) void mlp_kernel(const float* __restrict__ vab,
    const float* __restrict__ b1, const float* __restrict__ b2,
    const float* __restrict__ temp_p, char* __restrict__ ws, float* __restrict__ out){
  __shared__ __align__(16) unsigned short pb_lds[128 * 64];   // swizzled bf16, 16 KB
  __shared__ __align__(16) unsigned short h_lds[128 * 256];   // swizzled bf16, 64 KB
  const int tid = threadIdx.x;
  const int bb = blockIdx.x * 128;
  const float qscale = 1.44269504088896f / fmaxf(fabsf(temp_p[0]), 0.1f);

  for (int i = tid; i < 128 * 64; i += 256){                  // stage page bits (pad k 36..63 = 0)
    int r = i >> 6, k = i & 63;
    float v = (k < 36) ? vab[(size_t)(bb + r) * 48 + 12 + k] : 0.0f;
    int byte = (r * 128 + k * 2) ^ ((r & 7) << 4);
    *(unsigned short*)((char*)pb_lds + byte) = f2bf(v);
  }
  for (int i = tid; i < 128 * 12; i += 256){                  // offset-bit passthrough
    int r = i / 12, c = i - r * 12;
    out[(size_t)(bb + r) * 52 + c] = vab[(size_t)(bb + r) * 48 + c];
  }
  __syncthreads();

  const int lane = tid & 63, wv = tid >> 6;
  const int lo = lane & 31, hi = lane >> 5;
  const unsigned short* w1t = (const unsigned short*)(ws + OFF_W1T);

  // phase 1: h^T = W1^T @ pb^T
  #pragma unroll
  for (int art = 0; art < 2; ++art){
    const int hcol0 = (wv * 2 + art) * 32;
    bfr8 af[3];
    #pragma unroll
    for (int ks = 0; ks < 3; ++ks)
      af[ks] = *(const bfr8*)(w1t + (size_t)(hcol0 + lo) * 48 + 8 * hi + 16 * ks);
    for (int bct = 0; bct < 4; ++bct){
      f32x16v acc = zero16();
      #pragma unroll
      for (int ks = 0; ks < 3; ++ks){
        int row = bct * 32 + lo;
        int byte = row * 128 + ((16 * hi + 32 * ks) ^ ((row & 7) << 4));
        bfr8 bf = *(const bfr8*)((const char*)pb_lds + byte);
        acc = mfma32(af[ks], bf, acc);
      }
      int brow = bct * 32 + lo;
      #pragma unroll
      for (int w = 0; w < 4; ++w){
        u16x4 pk;
        #pragma unroll
        for (int rs = 0; rs < 4; ++rs){
          int hcol = hcol0 + rs + 8 * w + 4 * hi;
          float x = acc[4 * w + rs] + b1[hcol];
          // tanh-form gelu (|x| <~ 1 here; diff vs erf-gelu < 1e-4)
          float u = x * (0.7978845608028654f + 0.0356774081f * x * x);
          float t = exp2f(u * -2.885390081777927f);   // e^{-2u}
          float th = (1.0f - t) / (1.0f + t);
          pk[rs] = f2bf(0.5f * x * (1.0f + th));
        }
        int byte = (brow * 512 + (hcol0 + 8 * w + 4 * hi) * 2) ^ ((brow & 7) << 4);
        *(u16x4*)((char*)h_lds + byte) = pk;
      }
    }
  }
  __syncthreads();

  // phase 2: q^T = W2^T @ h^T -> Qws bf16 (folded invt*log2e)
  const unsigned short* w2t = (const unsigned short*)(ws + OFF_W2T);
  unsigned short* qws = (unsigned short*)(ws + OFF_Q);
  const int qcol0 = wv * 32;
  bfr8 af2[16];
  #pragma unroll
  for (int ks = 0; ks < 16; ++ks)
    af2[ks] = *(const bfr8*)(w2t + (size_t)(qcol0 + lo) * 256 + 8 * hi + 16 * ks);
  for (int bct = 0; bct < 4; ++bct){
    f32x16v acc = zero16();
    int brow = bct * 32 + lo;
    #pragma unroll
    for (int ks = 0; ks < 16; ++ks){
      int byte = brow * 512 + ((16 * hi + 32 * ks) ^ ((brow & 7) << 4));
      bfr8 bf = *(const bfr8*)((const char*)h_lds + byte);
      acc = mfma32(af2[ks], bf, acc);
    }
    #pragma unroll
    for (int w = 0; w < 4; ++w){
      u16x4 pk;
      #pragma unroll
      for (int rs = 0; rs < 4; ++rs){
        int qcol = qcol0 + rs + 8 * w + 4 * hi;
        pk[rs] = f2bf((acc[4 * w + rs] + b2[qcol]) * qscale);
      }
      *(u16x4*)(qws + (size_t)(bb + brow) * 128 + qcol0 + 8 * w + 4 * hi) = pk;
    }
  }
}

// ---------------- attention: 64 rows/wave dual-tile, K-split-in-WG ---------
// 512 WGs x 256 thr (4 waves). wave = (sub = rows sub*64..+64, half = K-half).
// Per chunk: two key-phases (0-31, 32-63); each K-frag ds_read feeds 2 Q-tiles.
// (R13 structure; V now fragment-packed -> contiguous wave reads)
__global__ __launch_bounds__(256, 2) void attn_kernel(const char* __restrict__ ws,
    float* __restrict__ out){
  __shared__ __align__(16) char smem[65536];    // [half][buf][16KB]; epilogue overlay

  const int tid = threadIdx.x;
  const int lane = tid & 63, wv = tid >> 6;
  const int half = wv >> 1, sub = wv & 1;
  const int lo = lane & 31, hi = lane >> 5;
  const int bb = blockIdx.x * 128;

  const unsigned short* qws = (const unsigned short*)(ws + OFF_Q);
  const char* kbase = ws + OFF_K;
  const char* va = ws + OFF_V;
  const char* vb = ws + OFF_VB;

  const int r0 = bb + sub * 64;
  bfr8 qfA[8], qfB[8];                          // two Q-tiles (B-frag: col=lo)
  #pragma unroll
  for (int ks = 0; ks < 8; ++ks){
    qfA[ks] = *(const bfr8*)(qws + (size_t)(r0 + lo) * 128 + 16 * ks + 8 * hi);
    qfB[ks] = *(const bfr8*)(qws + (size_t)(r0 + 32 + lo) * 128 + 16 * ks + 8 * hi);
  }

  f32x16v accA0 = zero16(), accA1 = zero16();
  f32x16v accB0 = zero16(), accB1 = zero16();

  char* myk = smem + half * 32768;
  const int cbase = half * 32;
  const int vbo = (hi * 16 + (lo & 15)) * 16;   // fragB lane offset (2-way broadcast)

  // prologue: stage this half's first chunk into buf 0 (wave covers sub*8KB)
  #pragma unroll
  for (int i = 0; i < 8; ++i)
    glds16(kbase + (size_t)cbase * 16384 + sub * 8192 + lane * 16 + i * 1024,
           myk + sub * 8192 + i * 1024);
  __syncthreads();

  for (int c = 0; c < 32; ++c){
    if (c < 31){                                // issue next-chunk DMA
      const char* src = kbase + (size_t)(cbase + c + 1) * 16384 + sub * 8192 + lane * 16;
      char* dst = myk + ((c + 1) & 1) * 16384 + sub * 8192;
      #pragma unroll
      for (int i = 0; i < 8; ++i) glds16(src + i * 1024, dst + i * 1024);
    }

    const char* kb = myk + (c & 1) * 16384;
    const int cg = cbase + c;

    #pragma unroll
    for (int ph = 0; ph < 2; ++ph){
      f32x16v sA = zero16(), sB = zero16();
      __builtin_amdgcn_s_setprio(1);
      #pragma unroll
      for (int ks = 0; ks < 8; ++ks){
        int cb = (32 * ks + 16 * hi) ^ ((lo & 15) << 4);   // (32+lo)&15 == lo&15
        bfr8 k0 = *(const bfr8*)(kb + (32 * ph + lo) * 256 + cb);
        sA = mfma32(k0, qfA[ks], sA);
        sB = mfma32(k0, qfB[ks], sB);
      }
      __builtin_amdgcn_s_setprio(0);

      const int t2 = 2 * cg + ph;               // 32-page tile index
      const char* vg  = va + (size_t)t2 * 2048 + lane * 16;
      const char* vgb = vb + (size_t)t2 * 1024 + vbo;
      bfr8 v00 = *(const bfr8*)(vg);            // pages 0-15, vcols 0-31
      bfr8 v01 = *(const bfr8*)(vg + 1024);     // pages 16-31
      bfr8 v10 = *(const bfr8*)(vgb);           // pages 0-15, vcols 32-47(+aug)
      bfr8 v11 = *(const bfr8*)(vgb + 512);     // pages 16-31

      bfr8 p0, p1, p2, p3;
      tile_pack(sA, p0, p1);
      tile_pack(sB, p2, p3);
      __builtin_amdgcn_s_setprio(1);
      accA0 = mfma32(p0, v00, accA0);  accA0 = mfma32(p1, v01, accA0);
      accA1 = mfma32(p0, v10, accA1);  accA1 = mfma32(p1, v11, accA1);
      accB0 = mfma32(p2, v00, accB0);  accB0 = mfma32(p3, v01, accB0);
      accB1 = mfma32(p2, v10, accB1);  accB1 = mfma32(p3, v11, accB1);
      __builtin_amdgcn_s_setprio(0);
    }
    __syncthreads();   // drains DMA (vmcnt) + LDS reads; next buffer ready
  }

  // ---- combine halves via LDS overlay (K buffers are dead now) ----
  float* comb0 = (float*)smem;                  // [128][32] f32, 16 KB
  float* comb1 = (float*)(smem + 16384);        // [128][12] f32, 6 KB
  if (half == 1){
    #pragma unroll
    for (int r = 0; r < 16; ++r){
      int rl = sub * 64 + (r & 3) + 8 * (r >> 2) + 4 * hi;
      comb0[rl * 32 + lo] = accA0[r];
      comb0[(rl + 32) * 32 + lo] = accB0[r];
      if (lo < 9){
        comb1[rl * 12 + lo] = accA1[r];
        comb1[(rl + 32) * 12 + lo] = accB1[r];
      }
    }
  }
  __syncthreads();
  if (half == 0){
    #pragma unroll
    for (int r = 0; r < 16; ++r){
      int rl = sub * 64 + (r & 3) + 8 * (r >> 2) + 4 * hi;
      {
        float n0 = accA0[r] + comb0[rl * 32 + lo];
        float a1 = accA1[r] + ((lo < 9) ? comb1[rl * 12 + lo] : 0.0f);
        float dn = __shfl(a1, (lane & 32) + 8, 64);   // denom = vcol 40 (lo==8)
        float di = 1.0f / dn;
        size_t q = (size_t)(bb + rl);
        out[q * 52 + 12 + lo] = sigmoidf_(n0 * di);
        if (lo < 8) out[q * 52 + 44 + lo] = sigmoidf_(a1 * di);
      }
      {
        float n0 = accB0[r] + comb0[(rl + 32) * 32 + lo];
        float a1 = accB1[r] + ((lo < 9) ? comb1[(rl + 32) * 12 + lo] : 0.0f);
        float dn = __shfl(a1, (lane & 32) + 8, 64);
        float di = 1.0f / dn;
        size_t q = (size_t)(bb + rl + 32);
        out[q * 52 + 12 + lo] = sigmoidf_(n0 * di);
        if (lo < 8) out[q * 52 + 44 + lo] = sigmoidf_(a1 * di);
      }
    }
  }
}

extern "C" void kernel_launch(void* const* d_in, const int* in_sizes, int n_in,
                              void* d_out, int out_size, void* d_ws, size_t ws_size,
                              hipStream_t stream){
  const float* vab      = (const float*)d_in[0];
  const float* mappings = (const float*)d_in[1];
  const float* keys     = (const float*)d_in[2];
  const float* perms    = (const float*)d_in[3];
  const float* W1       = (const float*)d_in[4];
  const float* b1       = (const float*)d_in[5];
  const float* W2       = (const float*)d_in[6];
  const float* b2       = (const float*)d_in[7];
  const float* temp     = (const float*)d_in[8];
  float* out = (float*)d_out;
  char*  ws  = (char*)d_ws;
  if (ws_size < WS_NEEDED) return;   // loud failure instead of OOB corruption

  prep_kernel<<<528, 256, 0, stream>>>(mappings, keys, perms, W1, W2, ws);
  mlp_kernel<<<512, 256, 0, stream>>>(vab, b1, b2, temp, ws, out);
  attn_kernel<<<512, 256, 0, stream>>>(ws, out);
}